// Round 10
// baseline (170.538 us; speedup 1.0000x reference)
//
#include <hip/hip_runtime.h>

#define DD 64
#define CAP 32  // fixed-stride CSR slots per node; csr lives in bufA upper half

typedef short bf16x8 __attribute__((ext_vector_type(8)));
typedef float f32x4 __attribute__((ext_vector_type(4)));

static __device__ __forceinline__ unsigned short f2bf(float f) {
  unsigned u = __float_as_uint(f);
  return (unsigned short)((u + 0x7fffu + ((u >> 16) & 1u)) >> 16);  // RNE
}
static __device__ __forceinline__ unsigned pack2bf(float lo, float hi) {
  return (((unsigned)f2bf(hi)) << 16) | (unsigned)f2bf(lo);
}

// flags bits: 1 = x2 consumed by heads (B), 2 = x1 needed (A)

// ============ zero flags (as ints) + cnt in one launch ============
__global__ __launch_bounds__(256) void k_zero(
    int* __restrict__ f4, int nf4, int* __restrict__ cnt, int N) {
  const int i = blockIdx.x * 256 + threadIdx.x;
  if (i < nf4) f4[i] = 0;
  if (i < N) cnt[i] = 0;
}

// ============ flagB pass ============
__global__ __launch_bounds__(256) void k_flag2(
    const int* __restrict__ sidx, const int* __restrict__ src,
    const int* __restrict__ dst, const int* __restrict__ aidx,
    unsigned char* __restrict__ flags, int NS, int B) {
  const int i = blockIdx.x * 256 + threadIdx.x;
  if (i < NS) {
    int e = sidx[i];
    flags[src[e]] = 1;
    flags[dst[e]] = 1;
  } else if (i < NS + B) {
    flags[aidx[i - NS]] = 1;
  }
}

// ============ flagA pass ============
__global__ __launch_bounds__(256) void k_flagA(
    const int* __restrict__ src, const int* __restrict__ dst,
    unsigned char* __restrict__ flags, int E) {
  const int e = blockIdx.x * 256 + threadIdx.x;
  if (e < E && (flags[dst[e]] & 1)) {
    int s = src[e];
    flags[s] = flags[s] | 2;  // benign race: all writers store same value
  }
}

// ============ shared MFMA GEMM body: yh[N x 64] = bf16(x @ W), bf16 output ============
// Layouts verified on-device: A: m=lane&15, k=16*g+4*(lane>>4)+..;
// D: row=(lane>>4)*4+reg, col=lane&15.
__device__ __forceinline__ void gemm_body(
    const float* __restrict__ x, const float* __restrict__ W,
    unsigned short* __restrict__ yh, int N, int bid, int nB) {
  __shared__ unsigned short wt[DD * DD];
  __shared__ float ys[4][16][68];
  for (int i = threadIdx.x; i < DD * DD; i += 256) {
    int k = i >> 6, n = i & 63;
    wt[n * DD + k] = f2bf(W[i]);
  }
  __syncthreads();
  const int wave = threadIdx.x >> 6;
  const int lane = threadIdx.x & 63;
  const int g = lane >> 4;
  const int m = lane & 15;
  bf16x8 bfr[8];
#pragma unroll
  for (int nt = 0; nt < 4; ++nt)
#pragma unroll
    for (int m2 = 0; m2 < 2; ++m2) {
      const int base = (nt * 16 + m) * DD + 4 * g + 32 * m2;
      ushort4 lo = *(const ushort4*)&wt[base];
      ushort4 hi = *(const ushort4*)&wt[base + 16];
      bf16x8 f;
      f[0] = (short)lo.x; f[1] = (short)lo.y; f[2] = (short)lo.z; f[3] = (short)lo.w;
      f[4] = (short)hi.x; f[5] = (short)hi.y; f[6] = (short)hi.z; f[7] = (short)hi.w;
      bfr[nt * 2 + m2] = f;
    }
  const int tiles = (N + 15) / 16;
  for (int t = bid * 4 + wave; t < tiles; t += nB * 4) {
    const int row = t * 16 + m;
    const int rsafe = (row < N) ? row : (N - 1);
    const float* xr = x + (size_t)rsafe * DD + 4 * g;
    float4 a0 = *(const float4*)(xr + 0);
    float4 a1 = *(const float4*)(xr + 16);
    float4 a2 = *(const float4*)(xr + 32);
    float4 a3 = *(const float4*)(xr + 48);
    bf16x8 af0, af1;
    af0[0] = (short)f2bf(a0.x); af0[1] = (short)f2bf(a0.y);
    af0[2] = (short)f2bf(a0.z); af0[3] = (short)f2bf(a0.w);
    af0[4] = (short)f2bf(a1.x); af0[5] = (short)f2bf(a1.y);
    af0[6] = (short)f2bf(a1.z); af0[7] = (short)f2bf(a1.w);
    af1[0] = (short)f2bf(a2.x); af1[1] = (short)f2bf(a2.y);
    af1[2] = (short)f2bf(a2.z); af1[3] = (short)f2bf(a2.w);
    af1[4] = (short)f2bf(a3.x); af1[5] = (short)f2bf(a3.y);
    af1[6] = (short)f2bf(a3.z); af1[7] = (short)f2bf(a3.w);
    f32x4 acc0 = {0.f, 0.f, 0.f, 0.f}, acc1 = acc0, acc2 = acc0, acc3 = acc0;
    acc0 = __builtin_amdgcn_mfma_f32_16x16x32_bf16(af0, bfr[0], acc0, 0, 0, 0);
    acc0 = __builtin_amdgcn_mfma_f32_16x16x32_bf16(af1, bfr[1], acc0, 0, 0, 0);
    acc1 = __builtin_amdgcn_mfma_f32_16x16x32_bf16(af0, bfr[2], acc1, 0, 0, 0);
    acc1 = __builtin_amdgcn_mfma_f32_16x16x32_bf16(af1, bfr[3], acc1, 0, 0, 0);
    acc2 = __builtin_amdgcn_mfma_f32_16x16x32_bf16(af0, bfr[4], acc2, 0, 0, 0);
    acc2 = __builtin_amdgcn_mfma_f32_16x16x32_bf16(af1, bfr[5], acc2, 0, 0, 0);
    acc3 = __builtin_amdgcn_mfma_f32_16x16x32_bf16(af0, bfr[6], acc3, 0, 0, 0);
    acc3 = __builtin_amdgcn_mfma_f32_16x16x32_bf16(af1, bfr[7], acc3, 0, 0, 0);
#pragma unroll
    for (int r = 0; r < 4; ++r) {
      ys[wave][4 * g + r][0 * 16 + m] = acc0[r];
      ys[wave][4 * g + r][1 * 16 + m] = acc1[r];
      ys[wave][4 * g + r][2 * 16 + m] = acc2[r];
      ys[wave][4 * g + r][3 * 16 + m] = acc3[r];
    }
    // same-wave cross-lane LDS RAW: compiler inserts lgkmcnt wait
    if (row < N) {
      unsigned short* yr = yh + (size_t)row * DD + g * 16;
      const float* s = &ys[wave][m][g * 16];
      uint4 olo, ohi;
      olo.x = pack2bf(s[0], s[1]);
      olo.y = pack2bf(s[2], s[3]);
      olo.z = pack2bf(s[4], s[5]);
      olo.w = pack2bf(s[6], s[7]);
      ohi.x = pack2bf(s[8], s[9]);
      ohi.y = pack2bf(s[10], s[11]);
      ohi.z = pack2bf(s[12], s[13]);
      ohi.w = pack2bf(s[14], s[15]);
      *(uint4*)yr = olo;
      *(uint4*)(yr + 8) = ohi;
    }
  }
}

// ============ fused: [0,GB) gemm1 | [GB,..) filtered CSR fill ============
// gemm1 (~16us, off critical path) hides inside the fill (~41us, atomic-bound):
// verified round 7 (combined 41.2us = fill-alone, MfmaUtil 0.66%).
__global__ __launch_bounds__(256) void k_pregf(
    const float* __restrict__ x, const float* __restrict__ W,
    unsigned short* __restrict__ yh, int N, int GB,
    const int* __restrict__ src, const int* __restrict__ dst,
    const unsigned char* __restrict__ flags, int* __restrict__ cnt,
    int* __restrict__ csr, int E) {
  const int bid = blockIdx.x;
  if (bid < GB) {
    gemm_body(x, W, yh, N, bid, GB);
  } else {
    int e = (bid - GB) * 256 + threadIdx.x;
    if (e < E) {
      int d = dst[e];
      if (flags[d]) {
        int slot = atomicAdd(&cnt[d], 1);
        if (slot < CAP) csr[d * CAP + slot] = src[e];
      }
    }
  }
}

// ============ fused gather1 + W1 transform ============
// Round-10 fixes (round-9 g1t stuck at 46us, latency-bound):
//  (a) ONE fully-unrolled 16-step exec-masked edge batch: all <=32 row loads
//      for a node issue as a single wave of independent loads (round 9 split
//      them into 8/2/1 sub-batches, each serialized on the previous acc).
//  (b) cross-node software pipeline: next node's {flags,cnt,slots} issued
//      before processing current node, hiding the meta round.
//  (c) W1 FMA chain split into 2 accumulators (64-deep -> 2x32).
__global__ __launch_bounds__(256) void k_g1t(
    const unsigned short* __restrict__ yh0, const int* __restrict__ cnt,
    const int* __restrict__ csr, const float* __restrict__ b0,
    const float* __restrict__ W1, unsigned short* __restrict__ yh1, int N,
    const unsigned char* __restrict__ flags) {
  __shared__ __align__(16) float Ws[DD * DD];  // 16 KB
  __shared__ __align__(16) float xs[4][DD];
  for (int i = threadIdx.x; i < DD * DD; i += 256) Ws[i] = W1[i];
  __syncthreads();
  const int wave = threadIdx.x >> 6;
  const int lane = threadIdx.x & 63;
  const int h = lane >> 5;  // edge-parity member
  const int c = lane & 31;  // uint column (elems 2c, 2c+1)
  const float b0r = b0[2 * c];
  const float b1r = b0[2 * c + 1];
  const int stride = gridDim.x * 4;
  int n = blockIdx.x * 4 + wave;
  if (n >= N) return;
  // prime meta for first node
  int fl = flags[n];
  int c2 = cnt[n];
  int slot = csr[n * CAP + c];
  while (n < N) {
    const int nn = n + stride;
    int fl_n = 0, c2_n = 0, slot_n = 0;
    if (nn < N) {  // prefetch next node's meta (independent of current work)
      fl_n = flags[nn];
      c2_n = cnt[nn];
      slot_n = csr[nn * CAP + c];
    }
    if (fl & 2) {
      const int cc = (c2 < CAP) ? c2 : CAP;
      float a0 = 0.f, a1 = 0.f;
#pragma unroll
      for (int j = 0; j < 16; ++j) {
        const int idx = 2 * j + h;  // h=0: even edges, h=1: odd edges
        const int s = __shfl(slot, idx);
        if (idx < cc) {  // exec-masked; all 16 loads independent -> one round
          unsigned v = *(const unsigned*)&yh0[(size_t)s * DD + 2 * c];
          a0 += __uint_as_float(v << 16);
          a1 += __uint_as_float(v & 0xffff0000u);
        }
      }
      a0 += __shfl_xor(a0, 32);
      a1 += __shfl_xor(a1, 32);
      if (h == 0) {
        xs[wave][2 * c] = fmaxf(a0 + b0r, 0.f);
        xs[wave][2 * c + 1] = fmaxf(a1 + b1r, 0.f);
      }
      // same-wave cross-lane LDS RAW: compiler inserts lgkmcnt wait
      float acc0 = 0.f, acc1 = 0.f;
#pragma unroll
      for (int k8 = 0; k8 < 8; ++k8) {
        float4 hA = *(const float4*)&xs[wave][k8 * 8];
        float4 hB = *(const float4*)&xs[wave][k8 * 8 + 4];
        acc0 = fmaf(hA.x, Ws[(k8 * 8 + 0) * DD + lane], acc0);
        acc0 = fmaf(hA.y, Ws[(k8 * 8 + 1) * DD + lane], acc0);
        acc0 = fmaf(hA.z, Ws[(k8 * 8 + 2) * DD + lane], acc0);
        acc0 = fmaf(hA.w, Ws[(k8 * 8 + 3) * DD + lane], acc0);
        acc1 = fmaf(hB.x, Ws[(k8 * 8 + 4) * DD + lane], acc1);
        acc1 = fmaf(hB.y, Ws[(k8 * 8 + 5) * DD + lane], acc1);
        acc1 = fmaf(hB.z, Ws[(k8 * 8 + 6) * DD + lane], acc1);
        acc1 = fmaf(hB.w, Ws[(k8 * 8 + 7) * DD + lane], acc1);
      }
      yh1[(size_t)n * DD + lane] = f2bf(acc0 + acc1);  // coalesced
    }
    n = nn;
    fl = fl_n;
    c2 = c2_n;
    slot = slot_n;
  }
}

// ============ bf16 gather: out[n] = relu(b + sum yh[csr(n)]) ============
// Single-round 16-step masked edge batch (same fix as k_g1t).
__global__ __launch_bounds__(256) void k_gather_h(
    const unsigned short* __restrict__ yh, const int* __restrict__ cnt,
    const int* __restrict__ csr, const float* __restrict__ b,
    float* __restrict__ outp, int N, const unsigned char* __restrict__ flags,
    int bit) {
  const int wave = threadIdx.x >> 6;
  const int lane = threadIdx.x & 63;
  const int h = lane >> 5;  // edge-parity member
  const int c = lane & 31;  // uint column (elems 2c, 2c+1)
  const int n = blockIdx.x * 4 + wave;
  if (n >= N) return;
  if (!(flags[n] & bit)) return;
  const float b0r = b[2 * c];
  const float b1r = b[2 * c + 1];
  int c2 = cnt[n];
  const int slot = csr[n * CAP + c];
  c2 = (c2 < CAP) ? c2 : CAP;
  float a0 = 0.f, a1 = 0.f;
#pragma unroll
  for (int j = 0; j < 16; ++j) {
    const int idx = 2 * j + h;
    const int s = __shfl(slot, idx);
    if (idx < c2) {
      unsigned v = *(const unsigned*)&yh[(size_t)s * DD + 2 * c];
      a0 += __uint_as_float(v << 16);
      a1 += __uint_as_float(v & 0xffff0000u);
    }
  }
  a0 += __shfl_xor(a0, 32);
  a1 += __shfl_xor(a1, 32);
  if (h == 0) {
    float2 r;
    r.x = fmaxf(a0 + b0r, 0.f);
    r.y = fmaxf(a1 + b1r, 0.f);
    *(float2*)&outp[(size_t)n * DD + 2 * c] = r;
  }
}

// ======================= fallback atomic path =======================
__global__ __launch_bounds__(256) void k_transform(
    const float* __restrict__ x, const float* __restrict__ W,
    float* __restrict__ y, int n_rows, int relu_in) {
  __shared__ __align__(16) float Ws[DD * DD];
  __shared__ __align__(16) float xs[4][DD];
  for (int i = threadIdx.x; i < DD * DD; i += 256) Ws[i] = W[i];
  __syncthreads();
  const int wave = threadIdx.x >> 6;
  const int lane = threadIdx.x & 63;
  for (int n = blockIdx.x * 4 + wave; n < n_rows; n += gridDim.x * 4) {
    float xv = x[n * DD + lane];
    if (relu_in) xv = fmaxf(xv, 0.f);
    xs[wave][lane] = xv;
    float acc = 0.f;
#pragma unroll
    for (int k4 = 0; k4 < DD / 4; ++k4) {
      float4 h4 = *(const float4*)&xs[wave][k4 * 4];
      acc = fmaf(h4.x, Ws[(k4 * 4 + 0) * DD + lane], acc);
      acc = fmaf(h4.y, Ws[(k4 * 4 + 1) * DD + lane], acc);
      acc = fmaf(h4.z, Ws[(k4 * 4 + 2) * DD + lane], acc);
      acc = fmaf(h4.w, Ws[(k4 * 4 + 3) * DD + lane], acc);
    }
    y[n * DD + lane] = acc;
  }
}

__global__ __launch_bounds__(256) void k_init_bias(
    float4* __restrict__ acc, const float* __restrict__ b, int total4) {
  const float4* b4 = (const float4*)b;
  for (int i = blockIdx.x * blockDim.x + threadIdx.x; i < total4;
       i += gridDim.x * blockDim.x)
    acc[i] = b4[i & 15];
}

__global__ __launch_bounds__(256) void k_scatter(
    const float* __restrict__ y, const int* __restrict__ src,
    const int* __restrict__ dst, float* __restrict__ acc, int E) {
  const int total = E * 16;
  for (int i = blockIdx.x * blockDim.x + threadIdx.x; i < total;
       i += gridDim.x * blockDim.x) {
    int e = i >> 4;
    int d4 = (i & 15) << 2;
    int s = src[e], dd = dst[e];
    float4 v = *(const float4*)&y[s * DD + d4];
    float* ap = &acc[dd * DD + d4];
    unsafeAtomicAdd(ap + 0, v.x);
    unsafeAtomicAdd(ap + 1, v.y);
    unsafeAtomicAdd(ap + 2, v.z);
    unsafeAtomicAdd(ap + 3, v.w);
  }
}

__global__ __launch_bounds__(256) void k_relu_inplace(float* __restrict__ p, int n) {
  for (int i = blockIdx.x * blockDim.x + threadIdx.x; i < n;
       i += gridDim.x * blockDim.x)
    p[i] = fmaxf(p[i], 0.f);
}

// ---------------- memory-management head ----------------
__global__ __launch_bounds__(256) void k_mm_head(
    const float* __restrict__ xact, const float* __restrict__ rel,
    const int* __restrict__ src, const int* __restrict__ dst,
    const int* __restrict__ etype, const int* __restrict__ sidx,
    const float* __restrict__ W0, const float* __restrict__ b0,
    const float* __restrict__ W1, const float* __restrict__ b1,
    const float* __restrict__ Wadv, const float* __restrict__ badv,
    const float* __restrict__ Wval, const float* __restrict__ bval,
    float* __restrict__ out, int NS) {
  __shared__ __align__(16) float W0s[192 * DD];  // 48 KB
  __shared__ float Wadvs[DD * 3], Wvals[DD], b0s[DD], b1s[DD], badvs[3];
  __shared__ __align__(16) float hs[4][192];
  __shared__ __align__(16) float h1s[4][DD];
  for (int i = threadIdx.x; i < 192 * DD; i += 256) W0s[i] = W0[i];
  for (int i = threadIdx.x; i < DD * 3; i += 256) Wadvs[i] = Wadv[i];
  if (threadIdx.x < DD) {
    Wvals[threadIdx.x] = Wval[threadIdx.x];
    b0s[threadIdx.x] = b0[threadIdx.x];
    b1s[threadIdx.x] = b1[threadIdx.x];
  }
  if (threadIdx.x < 3) badvs[threadIdx.x] = badv[threadIdx.x];
  __syncthreads();
  const float bv = bval[0];
  const int wave = threadIdx.x >> 6;
  const int lane = threadIdx.x & 63;
  for (int i = blockIdx.x * 4 + wave; i < NS; i += gridDim.x * 4) {
    int e = sidx[i];
    int s = src[e], dd = dst[e], t = etype[e];
    hs[wave][lane] = fmaxf(xact[s * DD + lane], 0.f);
    hs[wave][64 + lane] = rel[t * DD + lane];
    hs[wave][128 + lane] = fmaxf(xact[dd * DD + lane], 0.f);
    float acc = b0s[lane];
#pragma unroll
    for (int k4 = 0; k4 < 48; ++k4) {
      float4 h4 = *(const float4*)&hs[wave][k4 * 4];
      acc = fmaf(h4.x, W0s[(k4 * 4 + 0) * DD + lane], acc);
      acc = fmaf(h4.y, W0s[(k4 * 4 + 1) * DD + lane], acc);
      acc = fmaf(h4.z, W0s[(k4 * 4 + 2) * DD + lane], acc);
      acc = fmaf(h4.w, W0s[(k4 * 4 + 3) * DD + lane], acc);
    }
    h1s[wave][lane] = fmaxf(acc, 0.f);
    float acc2 = b1s[lane];
#pragma unroll
    for (int k4 = 0; k4 < 16; ++k4) {
      float4 h4 = *(const float4*)&h1s[wave][k4 * 4];
      acc2 = fmaf(h4.x, W1[(k4 * 4 + 0) * DD + lane], acc2);
      acc2 = fmaf(h4.y, W1[(k4 * 4 + 1) * DD + lane], acc2);
      acc2 = fmaf(h4.z, W1[(k4 * 4 + 2) * DD + lane], acc2);
      acc2 = fmaf(h4.w, W1[(k4 * 4 + 3) * DD + lane], acc2);
    }
    float h2 = fmaxf(acc2, 0.f);
    float p0 = h2 * Wadvs[lane * 3 + 0];
    float p1 = h2 * Wadvs[lane * 3 + 1];
    float p2 = h2 * Wadvs[lane * 3 + 2];
    float pv = h2 * Wvals[lane];
#pragma unroll
    for (int off = 32; off; off >>= 1) {
      p0 += __shfl_xor(p0, off);
      p1 += __shfl_xor(p1, off);
      p2 += __shfl_xor(p2, off);
      pv += __shfl_xor(pv, off);
    }
    if (lane == 0) {
      float a0 = p0 + badvs[0], a1 = p1 + badvs[1], a2 = p2 + badvs[2];
      float val = pv + bv;
      float m = (a0 + a1 + a2) * (1.f / 3.f);
      out[i * 3 + 0] = val + a0 - m;
      out[i * 3 + 1] = val + a1 - m;
      out[i * 3 + 2] = val + a2 - m;
    }
  }
}

// ---------------- explore head ----------------
__global__ __launch_bounds__(256) void k_ex_head(
    const float* __restrict__ xact, const int* __restrict__ aidx,
    const float* __restrict__ W0, const float* __restrict__ b0,
    const float* __restrict__ W1, const float* __restrict__ b1,
    const float* __restrict__ Wadv, const float* __restrict__ badv,
    const float* __restrict__ Wval, const float* __restrict__ bval,
    float* __restrict__ out, int B) {
  __shared__ __align__(16) float W0s[DD * DD], W1s[DD * DD];
  __shared__ float Wadvs[DD * 5], Wvals[DD], b0s[DD], b1s[DD], badvs[5];
  __shared__ __align__(16) float hs[4][DD], h1s[4][DD];
  for (int i = threadIdx.x; i < DD * DD; i += 256) {
    W0s[i] = W0[i];
    W1s[i] = W1[i];
  }
  for (int i = threadIdx.x; i < DD * 5; i += 256) Wadvs[i] = Wadv[i];
  if (threadIdx.x < DD) {
    Wvals[threadIdx.x] = Wval[threadIdx.x];
    b0s[threadIdx.x] = b0[threadIdx.x];
    b1s[threadIdx.x] = b1[threadIdx.x];
  }
  if (threadIdx.x < 5) badvs[threadIdx.x] = badv[threadIdx.x];
  __syncthreads();
  const float bv = bval[0];
  const int wave = threadIdx.x >> 6;
  const int lane = threadIdx.x & 63;
  const int i = blockIdx.x * 4 + wave;
  if (i >= B) return;
  int n = aidx[i];
  hs[wave][lane] = fmaxf(xact[n * DD + lane], 0.f);
  float acc = b0s[lane];
#pragma unroll
  for (int k4 = 0; k4 < 16; ++k4) {
    float4 h4 = *(const float4*)&hs[wave][k4 * 4];
    acc = fmaf(h4.x, W0s[(k4 * 4 + 0) * DD + lane], acc);
    acc = fmaf(h4.y, W0s[(k4 * 4 + 1) * DD + lane], acc);
    acc = fmaf(h4.z, W0s[(k4 * 4 + 2) * DD + lane], acc);
    acc = fmaf(h4.w, W0s[(k4 * 4 + 3) * DD + lane], acc);
  }
  h1s[wave][lane] = fmaxf(acc, 0.f);
  float acc2 = b1s[lane];
#pragma unroll
  for (int k4 = 0; k4 < 16; ++k4) {
    float4 h4 = *(const float4*)&h1s[wave][k4 * 4];
    acc2 = fmaf(h4.x, W1s[(k4 * 4 + 0) * DD + lane], acc2);
    acc2 = fmaf(h4.y, W1s[(k4 * 4 + 1) * DD + lane], acc2);
    acc2 = fmaf(h4.z, W1s[(k4 * 4 + 2) * DD + lane], acc2);
    acc2 = fmaf(h4.w, W1s[(k4 * 4 + 3) * DD + lane], acc2);
  }
  float h2 = fmaxf(acc2, 0.f);
  float p[6];
#pragma unroll
  for (int c = 0; c < 5; ++c) p[c] = h2 * Wadvs[lane * 5 + c];
  p[5] = h2 * Wvals[lane];
#pragma unroll
  for (int off = 32; off; off >>= 1)
#pragma unroll
    for (int c = 0; c < 6; ++c) p[c] += __shfl_xor(p[c], off);
  if (lane == 0) {
    float a[5];
    float m = 0.f;
#pragma unroll
    for (int c = 0; c < 5; ++c) {
      a[c] = p[c] + badvs[c];
      m += a[c];
    }
    m *= 0.2f;
    float val = p[5] + bv;
#pragma unroll
    for (int c = 0; c < 5; ++c) out[i * 5 + c] = val + a[c] - m;
  }
}

extern "C" void kernel_launch(void* const* d_in, const int* in_sizes, int n_in,
                              void* d_out, int out_size, void* d_ws, size_t ws_size,
                              hipStream_t stream) {
  const float* ent = (const float*)d_in[0];
  const float* rel = (const float*)d_in[1];
  const float* gcnW = (const float*)d_in[2];
  const float* gcnB = (const float*)d_in[3];
  const float* mmW0 = (const float*)d_in[4];
  const float* mmB0 = (const float*)d_in[5];
  const float* mmW1 = (const float*)d_in[6];
  const float* mmB1 = (const float*)d_in[7];
  const float* mmWa = (const float*)d_in[8];
  const float* mmBa = (const float*)d_in[9];
  const float* mmWv = (const float*)d_in[10];
  const float* mmBv = (const float*)d_in[11];
  const float* exW0 = (const float*)d_in[12];
  const float* exB0 = (const float*)d_in[13];
  const float* exW1 = (const float*)d_in[14];
  const float* exB1 = (const float*)d_in[15];
  const float* exWa = (const float*)d_in[16];
  const float* exBa = (const float*)d_in[17];
  const float* exWv = (const float*)d_in[18];
  const float* exBv = (const float*)d_in[19];
  const int* eidx = (const int*)d_in[20];
  const int* etype = (const int*)d_in[21];
  const int* sidx = (const int*)d_in[22];
  const int* aidx = (const int*)d_in[23];

  const int N = in_sizes[0] / DD;
  const int E = in_sizes[20] / 2;
  const int NS = in_sizes[22];
  const int B = in_sizes[23];
  const int* src = eidx;
  const int* dst = eidx + E;

  // Workspace layout:
  //   bufA: N*DD f32. Lower half = yh0 (gemm1 out, bf16). Upper half = csr.
  //   bufB: N*DD f32 = x2 (gather2 out at flagB rows; heads input).
  //   cnt : N ints
  //   flags: N bytes (padded to 4B multiple)
  //   yh1 : N*DD bf16 (k_g1t out) -- separate region: k_g1t reads yh0 while
  //         writing yh1, so in-place reuse of yh0 would race.
  float* bufA = (float*)d_ws;
  float* bufB = bufA + (size_t)N * DD;
  int* cnt = (int*)(bufB + (size_t)N * DD);
  unsigned char* flags = (unsigned char*)(cnt + N);
  const int nf4 = (N + 3) / 4;
  unsigned short* yh0 = (unsigned short*)bufA;
  int* csr = (int*)d_ws + (size_t)N * DD / 2;  // bufA upper half
  unsigned short* yh1 = (unsigned short*)((int*)flags + nf4);
  const size_t need = ((size_t)2 * N * DD + (size_t)N) * 4 + (size_t)nf4 * 4 +
                      (size_t)N * DD * 2;

  float* q_mm = (float*)d_out;
  float* q_ex = q_mm + (size_t)NS * 3;

  dim3 blk(256);
  const int eb = (E + 255) / 256;
  const int GB = 512;  // gemm blocks in k_pregf

  if (ws_size >= need) {
    // ---- zero flags + cnt ----
    k_zero<<<(N + 255) / 256, blk, 0, stream>>>((int*)flags, nf4, cnt, N);
    // ---- flagB from heads' consumers ----
    k_flag2<<<(NS + B + 255) / 256, blk, 0, stream>>>(sidx, src, dst, aidx, flags,
                                                      NS, B);
    // ---- flagA edge pass ----
    k_flagA<<<eb, blk, 0, stream>>>(src, dst, flags, E);
    // ---- fused: gemm1 (ent@W0 -> yh0 bf16) | filtered CSR fill ----
    k_pregf<<<GB + eb, blk, 0, stream>>>(ent, gcnW, yh0, N, GB, src, dst, flags,
                                         cnt, csr, E);
    // ---- fused layer1 gather + W1 transform at flagA (bit 2) rows ----
    k_g1t<<<4096, blk, 0, stream>>>(yh0, cnt, csr, gcnB, gcnW + DD * DD, yh1, N,
                                    flags);
    // ---- layer 2 gather: x2 = relu(b1 + gather yh1) at flagB (bit 1) ----
    k_gather_h<<<(N + 3) / 4, blk, 0, stream>>>(yh1, cnt, csr, gcnB + DD, bufB, N,
                                                flags, 1);
    // ---- heads (x2 = bufB at flagB nodes; fmax idempotent) ----
    k_mm_head<<<256, blk, 0, stream>>>(bufB, rel, src, dst, etype, sidx, mmW0,
                                       mmB0, mmW1, mmB1, mmWa, mmBa, mmWv, mmBv,
                                       q_mm, NS);
    k_ex_head<<<(B + 3) / 4, blk, 0, stream>>>(bufB, aidx, exW0, exB0, exW1, exB1,
                                               exWa, exBa, exWv, exBv, q_ex, B);
  } else {
    // ---- fallback: atomic scatter path ----
    k_transform<<<1024, blk, 0, stream>>>(ent, gcnW, bufA, N, 0);
    k_init_bias<<<1024, blk, 0, stream>>>((float4*)bufB, gcnB, N * 16);
    k_scatter<<<2048, blk, 0, stream>>>(bufA, src, dst, bufB, E);
    k_transform<<<1024, blk, 0, stream>>>(bufB, gcnW + DD * DD, bufA, N, 1);
    k_init_bias<<<1024, blk, 0, stream>>>((float4*)bufB, gcnB + DD, N * 16);
    k_scatter<<<2048, blk, 0, stream>>>(bufA, src, dst, bufB, E);
    k_relu_inplace<<<1024, blk, 0, stream>>>(bufB, N * DD);
    k_mm_head<<<256, blk, 0, stream>>>(bufB, rel, src, dst, etype, sidx, mmW0,
                                       mmB0, mmW1, mmB1, mmWa, mmBa, mmWv, mmBv,
                                       q_mm, NS);
    k_ex_head<<<(B + 3) / 4, blk, 0, stream>>>(bufB, aidx, exW0, exB0, exW1, exB1,
                                               exWa, exBa, exWv, exBv, q_ex, B);
  }
}

// Round 11
// 128.120 us; speedup vs baseline: 1.3311x; 1.3311x over previous
//
#include <hip/hip_runtime.h>

#define DD 64
#define CAP 32  // fixed-stride CSR slots per node; csr lives in bufA upper half

typedef short bf16x8 __attribute__((ext_vector_type(8)));
typedef float f32x4 __attribute__((ext_vector_type(4)));

static __device__ __forceinline__ unsigned short f2bf(float f) {
  unsigned u = __float_as_uint(f);
  return (unsigned short)((u + 0x7fffu + ((u >> 16) & 1u)) >> 16);  // RNE
}
static __device__ __forceinline__ unsigned pack2bf(float lo, float hi) {
  return (((unsigned)f2bf(hi)) << 16) | (unsigned)f2bf(lo);
}

// flags bits: 1 = x2 consumed by heads (B), 2 = x1 needed (A)

// ============ zero flags (as ints) + cnt in one launch ============
__global__ __launch_bounds__(256) void k_zero(
    int* __restrict__ f4, int nf4, int* __restrict__ cnt, int N) {
  const int i = blockIdx.x * 256 + threadIdx.x;
  if (i < nf4) f4[i] = 0;
  if (i < N) cnt[i] = 0;
}

// ============ flagB pass ============
__global__ __launch_bounds__(256) void k_flag2(
    const int* __restrict__ sidx, const int* __restrict__ src,
    const int* __restrict__ dst, const int* __restrict__ aidx,
    unsigned char* __restrict__ flags, int NS, int B) {
  const int i = blockIdx.x * 256 + threadIdx.x;
  if (i < NS) {
    int e = sidx[i];
    flags[src[e]] = 1;
    flags[dst[e]] = 1;
  } else if (i < NS + B) {
    flags[aidx[i - NS]] = 1;
  }
}

// ============ flagA pass ============
__global__ __launch_bounds__(256) void k_flagA(
    const int* __restrict__ src, const int* __restrict__ dst,
    unsigned char* __restrict__ flags, int E) {
  const int e = blockIdx.x * 256 + threadIdx.x;
  if (e < E && (flags[dst[e]] & 1)) {
    int s = src[e];
    flags[s] = flags[s] | 2;  // benign race: all writers store same value
  }
}

// ============ shared MFMA GEMM body: yh[N x 64] = bf16(x @ W), bf16 output ============
// Layouts verified on-device: A: m=lane&15, k=16*g+4*(lane>>4)+..;
// D: row=(lane>>4)*4+reg, col=lane&15.
__device__ __forceinline__ void gemm_body(
    const float* __restrict__ x, const float* __restrict__ W,
    unsigned short* __restrict__ yh, int N, int bid, int nB) {
  __shared__ unsigned short wt[DD * DD];
  __shared__ float ys[4][16][68];
  for (int i = threadIdx.x; i < DD * DD; i += 256) {
    int k = i >> 6, n = i & 63;
    wt[n * DD + k] = f2bf(W[i]);
  }
  __syncthreads();
  const int wave = threadIdx.x >> 6;
  const int lane = threadIdx.x & 63;
  const int g = lane >> 4;
  const int m = lane & 15;
  bf16x8 bfr[8];
#pragma unroll
  for (int nt = 0; nt < 4; ++nt)
#pragma unroll
    for (int m2 = 0; m2 < 2; ++m2) {
      const int base = (nt * 16 + m) * DD + 4 * g + 32 * m2;
      ushort4 lo = *(const ushort4*)&wt[base];
      ushort4 hi = *(const ushort4*)&wt[base + 16];
      bf16x8 f;
      f[0] = (short)lo.x; f[1] = (short)lo.y; f[2] = (short)lo.z; f[3] = (short)lo.w;
      f[4] = (short)hi.x; f[5] = (short)hi.y; f[6] = (short)hi.z; f[7] = (short)hi.w;
      bfr[nt * 2 + m2] = f;
    }
  const int tiles = (N + 15) / 16;
  for (int t = bid * 4 + wave; t < tiles; t += nB * 4) {
    const int row = t * 16 + m;
    const int rsafe = (row < N) ? row : (N - 1);
    const float* xr = x + (size_t)rsafe * DD + 4 * g;
    float4 a0 = *(const float4*)(xr + 0);
    float4 a1 = *(const float4*)(xr + 16);
    float4 a2 = *(const float4*)(xr + 32);
    float4 a3 = *(const float4*)(xr + 48);
    bf16x8 af0, af1;
    af0[0] = (short)f2bf(a0.x); af0[1] = (short)f2bf(a0.y);
    af0[2] = (short)f2bf(a0.z); af0[3] = (short)f2bf(a0.w);
    af0[4] = (short)f2bf(a1.x); af0[5] = (short)f2bf(a1.y);
    af0[6] = (short)f2bf(a1.z); af0[7] = (short)f2bf(a1.w);
    af1[0] = (short)f2bf(a2.x); af1[1] = (short)f2bf(a2.y);
    af1[2] = (short)f2bf(a2.z); af1[3] = (short)f2bf(a2.w);
    af1[4] = (short)f2bf(a3.x); af1[5] = (short)f2bf(a3.y);
    af1[6] = (short)f2bf(a3.z); af1[7] = (short)f2bf(a3.w);
    f32x4 acc0 = {0.f, 0.f, 0.f, 0.f}, acc1 = acc0, acc2 = acc0, acc3 = acc0;
    acc0 = __builtin_amdgcn_mfma_f32_16x16x32_bf16(af0, bfr[0], acc0, 0, 0, 0);
    acc0 = __builtin_amdgcn_mfma_f32_16x16x32_bf16(af1, bfr[1], acc0, 0, 0, 0);
    acc1 = __builtin_amdgcn_mfma_f32_16x16x32_bf16(af0, bfr[2], acc1, 0, 0, 0);
    acc1 = __builtin_amdgcn_mfma_f32_16x16x32_bf16(af1, bfr[3], acc1, 0, 0, 0);
    acc2 = __builtin_amdgcn_mfma_f32_16x16x32_bf16(af0, bfr[4], acc2, 0, 0, 0);
    acc2 = __builtin_amdgcn_mfma_f32_16x16x32_bf16(af1, bfr[5], acc2, 0, 0, 0);
    acc3 = __builtin_amdgcn_mfma_f32_16x16x32_bf16(af0, bfr[6], acc3, 0, 0, 0);
    acc3 = __builtin_amdgcn_mfma_f32_16x16x32_bf16(af1, bfr[7], acc3, 0, 0, 0);
#pragma unroll
    for (int r = 0; r < 4; ++r) {
      ys[wave][4 * g + r][0 * 16 + m] = acc0[r];
      ys[wave][4 * g + r][1 * 16 + m] = acc1[r];
      ys[wave][4 * g + r][2 * 16 + m] = acc2[r];
      ys[wave][4 * g + r][3 * 16 + m] = acc3[r];
    }
    // same-wave cross-lane LDS RAW: compiler inserts lgkmcnt wait
    if (row < N) {
      unsigned short* yr = yh + (size_t)row * DD + g * 16;
      const float* s = &ys[wave][m][g * 16];
      uint4 olo, ohi;
      olo.x = pack2bf(s[0], s[1]);
      olo.y = pack2bf(s[2], s[3]);
      olo.z = pack2bf(s[4], s[5]);
      olo.w = pack2bf(s[6], s[7]);
      ohi.x = pack2bf(s[8], s[9]);
      ohi.y = pack2bf(s[10], s[11]);
      ohi.z = pack2bf(s[12], s[13]);
      ohi.w = pack2bf(s[14], s[15]);
      *(uint4*)yr = olo;
      *(uint4*)(yr + 8) = ohi;
    }
  }
}

// ============ fused: [0,GB) gemm1 | [GB,..) filtered CSR fill ============
// gemm1 (~16us, off critical path) hides inside the fill (~41us, atomic-bound):
// verified round 7 (combined 41.2us = fill-alone, MfmaUtil 0.66%).
__global__ __launch_bounds__(256) void k_pregf(
    const float* __restrict__ x, const float* __restrict__ W,
    unsigned short* __restrict__ yh, int N, int GB,
    const int* __restrict__ src, const int* __restrict__ dst,
    const unsigned char* __restrict__ flags, int* __restrict__ cnt,
    int* __restrict__ csr, int E) {
  const int bid = blockIdx.x;
  if (bid < GB) {
    gemm_body(x, W, yh, N, bid, GB);
  } else {
    int e = (bid - GB) * 256 + threadIdx.x;
    if (e < E) {
      int d = dst[e];
      if (flags[d]) {
        int slot = atomicAdd(&cnt[d], 1);
        if (slot < CAP) csr[d * CAP + slot] = src[e];
      }
    }
  }
}

// ============ fused gather1 + W1 transform (round-9 form, measured 46us) ============
// Round-10 post-mortem: prefetch pipeline + masked 16-step batch raised VGPR
// 24->52, occupancy 53->31%, dur 46->92us. REVERTED. In latency-bound gather,
// occupancy + simple codegen beat manual ILP (the 8-edge batch already issues
// 4 independent loads/lane with register-resident addresses). Only surviving
// round-10 piece: W1 FMA chain split into 2 accumulators (register-neutral).
__global__ __launch_bounds__(256) void k_g1t(
    const unsigned short* __restrict__ yh0, const int* __restrict__ cnt,
    const int* __restrict__ csr, const float* __restrict__ b0,
    const float* __restrict__ W1, unsigned short* __restrict__ yh1, int N,
    const unsigned char* __restrict__ flags) {
  __shared__ __align__(16) float Ws[DD * DD];  // 16 KB
  __shared__ __align__(16) float xs[4][DD];
  for (int i = threadIdx.x; i < DD * DD; i += 256) Ws[i] = W1[i];
  __syncthreads();
  const int wave = threadIdx.x >> 6;
  const int lane = threadIdx.x & 63;
  const int h = lane >> 5;  // edge-parity member
  const int c = lane & 31;  // uint column (elems 2c, 2c+1)
  const float b0r = b0[2 * c];
  const float b1r = b0[2 * c + 1];
  for (int n = blockIdx.x * 4 + wave; n < N; n += gridDim.x * 4) {
    // --- single round: flags + cnt + all slots (mutually independent) ---
    const int fl = flags[n];
    int c2 = cnt[n];
    const int slot = csr[n * CAP + c];  // lane c holds slot c (mirrored in h=1)
    if (!(fl & 2)) continue;
    c2 = (c2 < CAP) ? c2 : CAP;
    float a0 = 0.f, a1 = 0.f;
    int j = 0;
    for (; j + 8 <= c2; j += 8) {
      const int sA = __shfl(slot, j + 0 + h);
      const int sB = __shfl(slot, j + 2 + h);
      const int sC = __shfl(slot, j + 4 + h);
      const int sD = __shfl(slot, j + 6 + h);
      unsigned vA = *(const unsigned*)&yh0[(size_t)sA * DD + 2 * c];
      unsigned vB = *(const unsigned*)&yh0[(size_t)sB * DD + 2 * c];
      unsigned vC = *(const unsigned*)&yh0[(size_t)sC * DD + 2 * c];
      unsigned vD = *(const unsigned*)&yh0[(size_t)sD * DD + 2 * c];
      a0 += (__uint_as_float(vA << 16) + __uint_as_float(vB << 16)) +
            (__uint_as_float(vC << 16) + __uint_as_float(vD << 16));
      a1 += (__uint_as_float(vA & 0xffff0000u) + __uint_as_float(vB & 0xffff0000u)) +
            (__uint_as_float(vC & 0xffff0000u) + __uint_as_float(vD & 0xffff0000u));
    }
    for (; j + 2 <= c2; j += 2) {
      const int sA = __shfl(slot, j + h);
      unsigned vA = *(const unsigned*)&yh0[(size_t)sA * DD + 2 * c];
      a0 += __uint_as_float(vA << 16);
      a1 += __uint_as_float(vA & 0xffff0000u);
    }
    const int sT = __shfl(slot, j);  // hoisted out of divergent branch
    if (j < c2 && h == 0) {
      unsigned vA = *(const unsigned*)&yh0[(size_t)sT * DD + 2 * c];
      a0 += __uint_as_float(vA << 16);
      a1 += __uint_as_float(vA & 0xffff0000u);
    }
    a0 += __shfl_xor(a0, 32);
    a1 += __shfl_xor(a1, 32);
    if (h == 0) {
      xs[wave][2 * c] = fmaxf(a0 + b0r, 0.f);
      xs[wave][2 * c + 1] = fmaxf(a1 + b1r, 0.f);
    }
    // same-wave cross-lane LDS RAW: compiler inserts lgkmcnt wait
    float acc0 = 0.f, acc1 = 0.f;
#pragma unroll
    for (int k8 = 0; k8 < 8; ++k8) {
      float4 hA = *(const float4*)&xs[wave][k8 * 8];
      float4 hB = *(const float4*)&xs[wave][k8 * 8 + 4];
      acc0 = fmaf(hA.x, Ws[(k8 * 8 + 0) * DD + lane], acc0);
      acc0 = fmaf(hA.y, Ws[(k8 * 8 + 1) * DD + lane], acc0);
      acc0 = fmaf(hA.z, Ws[(k8 * 8 + 2) * DD + lane], acc0);
      acc0 = fmaf(hA.w, Ws[(k8 * 8 + 3) * DD + lane], acc0);
      acc1 = fmaf(hB.x, Ws[(k8 * 8 + 4) * DD + lane], acc1);
      acc1 = fmaf(hB.y, Ws[(k8 * 8 + 5) * DD + lane], acc1);
      acc1 = fmaf(hB.z, Ws[(k8 * 8 + 6) * DD + lane], acc1);
      acc1 = fmaf(hB.w, Ws[(k8 * 8 + 7) * DD + lane], acc1);
    }
    yh1[(size_t)n * DD + lane] = f2bf(acc0 + acc1);  // coalesced
  }
}

// ============ bf16 gather: out[n] = relu(b + sum yh[csr(n)]) ============
// Round-9 form (round-10's masked batch reverted with k_g1t).
__global__ __launch_bounds__(256) void k_gather_h(
    const unsigned short* __restrict__ yh, const int* __restrict__ cnt,
    const int* __restrict__ csr, const float* __restrict__ b,
    float* __restrict__ outp, int N, const unsigned char* __restrict__ flags,
    int bit) {
  const int wave = threadIdx.x >> 6;
  const int lane = threadIdx.x & 63;
  const int h = lane >> 5;  // edge-parity member
  const int c = lane & 31;  // uint column (elems 2c, 2c+1)
  const int n = blockIdx.x * 4 + wave;
  if (n >= N) return;
  if (!(flags[n] & bit)) return;
  const float b0r = b[2 * c];
  const float b1r = b[2 * c + 1];
  // one round: cnt + all slots (independent)
  int c2 = cnt[n];
  const int slot = csr[n * CAP + c];
  c2 = (c2 < CAP) ? c2 : CAP;
  float a0 = 0.f, a1 = 0.f;
  int j = 0;
  for (; j + 8 <= c2; j += 8) {
    const int sA = __shfl(slot, j + 0 + h);
    const int sB = __shfl(slot, j + 2 + h);
    const int sC = __shfl(slot, j + 4 + h);
    const int sD = __shfl(slot, j + 6 + h);
    unsigned vA = *(const unsigned*)&yh[(size_t)sA * DD + 2 * c];
    unsigned vB = *(const unsigned*)&yh[(size_t)sB * DD + 2 * c];
    unsigned vC = *(const unsigned*)&yh[(size_t)sC * DD + 2 * c];
    unsigned vD = *(const unsigned*)&yh[(size_t)sD * DD + 2 * c];
    a0 += (__uint_as_float(vA << 16) + __uint_as_float(vB << 16)) +
          (__uint_as_float(vC << 16) + __uint_as_float(vD << 16));
    a1 += (__uint_as_float(vA & 0xffff0000u) + __uint_as_float(vB & 0xffff0000u)) +
          (__uint_as_float(vC & 0xffff0000u) + __uint_as_float(vD & 0xffff0000u));
  }
  for (; j + 2 <= c2; j += 2) {
    const int sA = __shfl(slot, j + h);
    unsigned vA = *(const unsigned*)&yh[(size_t)sA * DD + 2 * c];
    a0 += __uint_as_float(vA << 16);
    a1 += __uint_as_float(vA & 0xffff0000u);
  }
  const int sT = __shfl(slot, j);
  if (j < c2 && h == 0) {
    unsigned vA = *(const unsigned*)&yh[(size_t)sT * DD + 2 * c];
    a0 += __uint_as_float(vA << 16);
    a1 += __uint_as_float(vA & 0xffff0000u);
  }
  a0 += __shfl_xor(a0, 32);
  a1 += __shfl_xor(a1, 32);
  if (h == 0) {
    float2 r;
    r.x = fmaxf(a0 + b0r, 0.f);
    r.y = fmaxf(a1 + b1r, 0.f);
    *(float2*)&outp[(size_t)n * DD + 2 * c] = r;
  }
}

// ======================= fallback atomic path =======================
__global__ __launch_bounds__(256) void k_transform(
    const float* __restrict__ x, const float* __restrict__ W,
    float* __restrict__ y, int n_rows, int relu_in) {
  __shared__ __align__(16) float Ws[DD * DD];
  __shared__ __align__(16) float xs[4][DD];
  for (int i = threadIdx.x; i < DD * DD; i += 256) Ws[i] = W[i];
  __syncthreads();
  const int wave = threadIdx.x >> 6;
  const int lane = threadIdx.x & 63;
  for (int n = blockIdx.x * 4 + wave; n < n_rows; n += gridDim.x * 4) {
    float xv = x[n * DD + lane];
    if (relu_in) xv = fmaxf(xv, 0.f);
    xs[wave][lane] = xv;
    float acc = 0.f;
#pragma unroll
    for (int k4 = 0; k4 < DD / 4; ++k4) {
      float4 h4 = *(const float4*)&xs[wave][k4 * 4];
      acc = fmaf(h4.x, Ws[(k4 * 4 + 0) * DD + lane], acc);
      acc = fmaf(h4.y, Ws[(k4 * 4 + 1) * DD + lane], acc);
      acc = fmaf(h4.z, Ws[(k4 * 4 + 2) * DD + lane], acc);
      acc = fmaf(h4.w, Ws[(k4 * 4 + 3) * DD + lane], acc);
    }
    y[n * DD + lane] = acc;
  }
}

__global__ __launch_bounds__(256) void k_init_bias(
    float4* __restrict__ acc, const float* __restrict__ b, int total4) {
  const float4* b4 = (const float4*)b;
  for (int i = blockIdx.x * blockDim.x + threadIdx.x; i < total4;
       i += gridDim.x * blockDim.x)
    acc[i] = b4[i & 15];
}

__global__ __launch_bounds__(256) void k_scatter(
    const float* __restrict__ y, const int* __restrict__ src,
    const int* __restrict__ dst, float* __restrict__ acc, int E) {
  const int total = E * 16;
  for (int i = blockIdx.x * blockDim.x + threadIdx.x; i < total;
       i += gridDim.x * blockDim.x) {
    int e = i >> 4;
    int d4 = (i & 15) << 2;
    int s = src[e], dd = dst[e];
    float4 v = *(const float4*)&y[s * DD + d4];
    float* ap = &acc[dd * DD + d4];
    unsafeAtomicAdd(ap + 0, v.x);
    unsafeAtomicAdd(ap + 1, v.y);
    unsafeAtomicAdd(ap + 2, v.z);
    unsafeAtomicAdd(ap + 3, v.w);
  }
}

__global__ __launch_bounds__(256) void k_relu_inplace(float* __restrict__ p, int n) {
  for (int i = blockIdx.x * blockDim.x + threadIdx.x; i < n;
       i += gridDim.x * blockDim.x)
    p[i] = fmaxf(p[i], 0.f);
}

// ---------------- memory-management head ----------------
__global__ __launch_bounds__(256) void k_mm_head(
    const float* __restrict__ xact, const float* __restrict__ rel,
    const int* __restrict__ src, const int* __restrict__ dst,
    const int* __restrict__ etype, const int* __restrict__ sidx,
    const float* __restrict__ W0, const float* __restrict__ b0,
    const float* __restrict__ W1, const float* __restrict__ b1,
    const float* __restrict__ Wadv, const float* __restrict__ badv,
    const float* __restrict__ Wval, const float* __restrict__ bval,
    float* __restrict__ out, int NS) {
  __shared__ __align__(16) float W0s[192 * DD];  // 48 KB
  __shared__ float Wadvs[DD * 3], Wvals[DD], b0s[DD], b1s[DD], badvs[3];
  __shared__ __align__(16) float hs[4][192];
  __shared__ __align__(16) float h1s[4][DD];
  for (int i = threadIdx.x; i < 192 * DD; i += 256) W0s[i] = W0[i];
  for (int i = threadIdx.x; i < DD * 3; i += 256) Wadvs[i] = Wadv[i];
  if (threadIdx.x < DD) {
    Wvals[threadIdx.x] = Wval[threadIdx.x];
    b0s[threadIdx.x] = b0[threadIdx.x];
    b1s[threadIdx.x] = b1[threadIdx.x];
  }
  if (threadIdx.x < 3) badvs[threadIdx.x] = badv[threadIdx.x];
  __syncthreads();
  const float bv = bval[0];
  const int wave = threadIdx.x >> 6;
  const int lane = threadIdx.x & 63;
  for (int i = blockIdx.x * 4 + wave; i < NS; i += gridDim.x * 4) {
    int e = sidx[i];
    int s = src[e], dd = dst[e], t = etype[e];
    hs[wave][lane] = fmaxf(xact[s * DD + lane], 0.f);
    hs[wave][64 + lane] = rel[t * DD + lane];
    hs[wave][128 + lane] = fmaxf(xact[dd * DD + lane], 0.f);
    float acc = b0s[lane];
#pragma unroll
    for (int k4 = 0; k4 < 48; ++k4) {
      float4 h4 = *(const float4*)&hs[wave][k4 * 4];
      acc = fmaf(h4.x, W0s[(k4 * 4 + 0) * DD + lane], acc);
      acc = fmaf(h4.y, W0s[(k4 * 4 + 1) * DD + lane], acc);
      acc = fmaf(h4.z, W0s[(k4 * 4 + 2) * DD + lane], acc);
      acc = fmaf(h4.w, W0s[(k4 * 4 + 3) * DD + lane], acc);
    }
    h1s[wave][lane] = fmaxf(acc, 0.f);
    float acc2 = b1s[lane];
#pragma unroll
    for (int k4 = 0; k4 < 16; ++k4) {
      float4 h4 = *(const float4*)&h1s[wave][k4 * 4];
      acc2 = fmaf(h4.x, W1[(k4 * 4 + 0) * DD + lane], acc2);
      acc2 = fmaf(h4.y, W1[(k4 * 4 + 1) * DD + lane], acc2);
      acc2 = fmaf(h4.z, W1[(k4 * 4 + 2) * DD + lane], acc2);
      acc2 = fmaf(h4.w, W1[(k4 * 4 + 3) * DD + lane], acc2);
    }
    float h2 = fmaxf(acc2, 0.f);
    float p0 = h2 * Wadvs[lane * 3 + 0];
    float p1 = h2 * Wadvs[lane * 3 + 1];
    float p2 = h2 * Wadvs[lane * 3 + 2];
    float pv = h2 * Wvals[lane];
#pragma unroll
    for (int off = 32; off; off >>= 1) {
      p0 += __shfl_xor(p0, off);
      p1 += __shfl_xor(p1, off);
      p2 += __shfl_xor(p2, off);
      pv += __shfl_xor(pv, off);
    }
    if (lane == 0) {
      float a0 = p0 + badvs[0], a1 = p1 + badvs[1], a2 = p2 + badvs[2];
      float val = pv + bv;
      float m = (a0 + a1 + a2) * (1.f / 3.f);
      out[i * 3 + 0] = val + a0 - m;
      out[i * 3 + 1] = val + a1 - m;
      out[i * 3 + 2] = val + a2 - m;
    }
  }
}

// ---------------- explore head ----------------
__global__ __launch_bounds__(256) void k_ex_head(
    const float* __restrict__ xact, const int* __restrict__ aidx,
    const float* __restrict__ W0, const float* __restrict__ b0,
    const float* __restrict__ W1, const float* __restrict__ b1,
    const float* __restrict__ Wadv, const float* __restrict__ badv,
    const float* __restrict__ Wval, const float* __restrict__ bval,
    float* __restrict__ out, int B) {
  __shared__ __align__(16) float W0s[DD * DD], W1s[DD * DD];
  __shared__ float Wadvs[DD * 5], Wvals[DD], b0s[DD], b1s[DD], badvs[5];
  __shared__ __align__(16) float hs[4][DD], h1s[4][DD];
  for (int i = threadIdx.x; i < DD * DD; i += 256) {
    W0s[i] = W0[i];
    W1s[i] = W1[i];
  }
  for (int i = threadIdx.x; i < DD * 5; i += 256) Wadvs[i] = Wadv[i];
  if (threadIdx.x < DD) {
    Wvals[threadIdx.x] = Wval[threadIdx.x];
    b0s[threadIdx.x] = b0[threadIdx.x];
    b1s[threadIdx.x] = b1[threadIdx.x];
  }
  if (threadIdx.x < 5) badvs[threadIdx.x] = badv[threadIdx.x];
  __syncthreads();
  const float bv = bval[0];
  const int wave = threadIdx.x >> 6;
  const int lane = threadIdx.x & 63;
  const int i = blockIdx.x * 4 + wave;
  if (i >= B) return;
  int n = aidx[i];
  hs[wave][lane] = fmaxf(xact[n * DD + lane], 0.f);
  float acc = b0s[lane];
#pragma unroll
  for (int k4 = 0; k4 < 16; ++k4) {
    float4 h4 = *(const float4*)&hs[wave][k4 * 4];
    acc = fmaf(h4.x, W0s[(k4 * 4 + 0) * DD + lane], acc);
    acc = fmaf(h4.y, W0s[(k4 * 4 + 1) * DD + lane], acc);
    acc = fmaf(h4.z, W0s[(k4 * 4 + 2) * DD + lane], acc);
    acc = fmaf(h4.w, W0s[(k4 * 4 + 3) * DD + lane], acc);
  }
  h1s[wave][lane] = fmaxf(acc, 0.f);
  float acc2 = b1s[lane];
#pragma unroll
  for (int k4 = 0; k4 < 16; ++k4) {
    float4 h4 = *(const float4*)&h1s[wave][k4 * 4];
    acc2 = fmaf(h4.x, W1s[(k4 * 4 + 0) * DD + lane], acc2);
    acc2 = fmaf(h4.y, W1s[(k4 * 4 + 1) * DD + lane], acc2);
    acc2 = fmaf(h4.z, W1s[(k4 * 4 + 2) * DD + lane], acc2);
    acc2 = fmaf(h4.w, W1s[(k4 * 4 + 3) * DD + lane], acc2);
  }
  float h2 = fmaxf(acc2, 0.f);
  float p[6];
#pragma unroll
  for (int c = 0; c < 5; ++c) p[c] = h2 * Wadvs[lane * 5 + c];
  p[5] = h2 * Wvals[lane];
#pragma unroll
  for (int off = 32; off; off >>= 1)
#pragma unroll
    for (int c = 0; c < 6; ++c) p[c] += __shfl_xor(p[c], off);
  if (lane == 0) {
    float a[5];
    float m = 0.f;
#pragma unroll
    for (int c = 0; c < 5; ++c) {
      a[c] = p[c] + badvs[c];
      m += a[c];
    }
    m *= 0.2f;
    float val = p[5] + bv;
#pragma unroll
    for (int c = 0; c < 5; ++c) out[i * 5 + c] = val + a[c] - m;
  }
}

extern "C" void kernel_launch(void* const* d_in, const int* in_sizes, int n_in,
                              void* d_out, int out_size, void* d_ws, size_t ws_size,
                              hipStream_t stream) {
  const float* ent = (const float*)d_in[0];
  const float* rel = (const float*)d_in[1];
  const float* gcnW = (const float*)d_in[2];
  const float* gcnB = (const float*)d_in[3];
  const float* mmW0 = (const float*)d_in[4];
  const float* mmB0 = (const float*)d_in[5];
  const float* mmW1 = (const float*)d_in[6];
  const float* mmB1 = (const float*)d_in[7];
  const float* mmWa = (const float*)d_in[8];
  const float* mmBa = (const float*)d_in[9];
  const float* mmWv = (const float*)d_in[10];
  const float* mmBv = (const float*)d_in[11];
  const float* exW0 = (const float*)d_in[12];
  const float* exB0 = (const float*)d_in[13];
  const float* exW1 = (const float*)d_in[14];
  const float* exB1 = (const float*)d_in[15];
  const float* exWa = (const float*)d_in[16];
  const float* exBa = (const float*)d_in[17];
  const float* exWv = (const float*)d_in[18];
  const float* exBv = (const float*)d_in[19];
  const int* eidx = (const int*)d_in[20];
  const int* etype = (const int*)d_in[21];
  const int* sidx = (const int*)d_in[22];
  const int* aidx = (const int*)d_in[23];

  const int N = in_sizes[0] / DD;
  const int E = in_sizes[20] / 2;
  const int NS = in_sizes[22];
  const int B = in_sizes[23];
  const int* src = eidx;
  const int* dst = eidx + E;

  // Workspace layout:
  //   bufA: N*DD f32. Lower half = yh0 (gemm1 out, bf16). Upper half = csr.
  //   bufB: N*DD f32 = x2 (gather2 out at flagB rows; heads input).
  //   cnt : N ints
  //   flags: N bytes (padded to 4B multiple)
  //   yh1 : N*DD bf16 (k_g1t out) -- separate region: k_g1t reads yh0 while
  //         writing yh1, so in-place reuse of yh0 would race.
  float* bufA = (float*)d_ws;
  float* bufB = bufA + (size_t)N * DD;
  int* cnt = (int*)(bufB + (size_t)N * DD);
  unsigned char* flags = (unsigned char*)(cnt + N);
  const int nf4 = (N + 3) / 4;
  unsigned short* yh0 = (unsigned short*)bufA;
  int* csr = (int*)d_ws + (size_t)N * DD / 2;  // bufA upper half
  unsigned short* yh1 = (unsigned short*)((int*)flags + nf4);
  const size_t need = ((size_t)2 * N * DD + (size_t)N) * 4 + (size_t)nf4 * 4 +
                      (size_t)N * DD * 2;

  float* q_mm = (float*)d_out;
  float* q_ex = q_mm + (size_t)NS * 3;

  dim3 blk(256);
  const int eb = (E + 255) / 256;
  const int GB = 512;  // gemm blocks in k_pregf

  if (ws_size >= need) {
    // ---- zero flags + cnt ----
    k_zero<<<(N + 255) / 256, blk, 0, stream>>>((int*)flags, nf4, cnt, N);
    // ---- flagB from heads' consumers ----
    k_flag2<<<(NS + B + 255) / 256, blk, 0, stream>>>(sidx, src, dst, aidx, flags,
                                                      NS, B);
    // ---- flagA edge pass ----
    k_flagA<<<eb, blk, 0, stream>>>(src, dst, flags, E);
    // ---- fused: gemm1 (ent@W0 -> yh0 bf16) | filtered CSR fill ----
    k_pregf<<<GB + eb, blk, 0, stream>>>(ent, gcnW, yh0, N, GB, src, dst, flags,
                                         cnt, csr, E);
    // ---- fused layer1 gather + W1 transform at flagA (bit 2) rows ----
    k_g1t<<<4096, blk, 0, stream>>>(yh0, cnt, csr, gcnB, gcnW + DD * DD, yh1, N,
                                    flags);
    // ---- layer 2 gather: x2 = relu(b1 + gather yh1) at flagB (bit 1) ----
    k_gather_h<<<(N + 3) / 4, blk, 0, stream>>>(yh1, cnt, csr, gcnB + DD, bufB, N,
                                                flags, 1);
    // ---- heads (x2 = bufB at flagB nodes; fmax idempotent) ----
    k_mm_head<<<256, blk, 0, stream>>>(bufB, rel, src, dst, etype, sidx, mmW0,
                                       mmB0, mmW1, mmB1, mmWa, mmBa, mmWv, mmBv,
                                       q_mm, NS);
    k_ex_head<<<(B + 3) / 4, blk, 0, stream>>>(bufB, aidx, exW0, exB0, exW1, exB1,
                                               exWa, exBa, exWv, exBv, q_ex, B);
  } else {
    // ---- fallback: atomic scatter path ----
    k_transform<<<1024, blk, 0, stream>>>(ent, gcnW, bufA, N, 0);
    k_init_bias<<<1024, blk, 0, stream>>>((float4*)bufB, gcnB, N * 16);
    k_scatter<<<2048, blk, 0, stream>>>(bufA, src, dst, bufB, E);
    k_transform<<<1024, blk, 0, stream>>>(bufB, gcnW + DD * DD, bufA, N, 1);
    k_init_bias<<<1024, blk, 0, stream>>>((float4*)bufB, gcnB + DD, N * 16);
    k_scatter<<<2048, blk, 0, stream>>>(bufA, src, dst, bufB, E);
    k_relu_inplace<<<1024, blk, 0, stream>>>(bufB, N * DD);
    k_mm_head<<<256, blk, 0, stream>>>(bufB, rel, src, dst, etype, sidx, mmW0,
                                       mmB0, mmW1, mmB1, mmWa, mmBa, mmWv, mmBv,
                                       q_mm, NS);
    k_ex_head<<<(B + 3) / 4, blk, 0, stream>>>(bufB, aidx, exW0, exB0, exW1, exB1,
                                               exWa, exBa, exWv, exBv, q_ex, B);
  }
}

// Round 12
// 126.126 us; speedup vs baseline: 1.3521x; 1.0158x over previous
//
#include <hip/hip_runtime.h>

#define DD 64
#define CAP 32  // fixed-stride CSR slots per node; csr lives in bufA upper half

typedef short bf16x8 __attribute__((ext_vector_type(8)));
typedef float f32x4 __attribute__((ext_vector_type(4)));

static __device__ __forceinline__ unsigned short f2bf(float f) {
  unsigned u = __float_as_uint(f);
  return (unsigned short)((u + 0x7fffu + ((u >> 16) & 1u)) >> 16);  // RNE
}
static __device__ __forceinline__ unsigned pack2bf(float lo, float hi) {
  return (((unsigned)f2bf(hi)) << 16) | (unsigned)f2bf(lo);
}

// flags bits: 1 = x2 consumed by heads (B), 2 = x1 needed (A)

// ============ zero flags (as ints) + cnt in one launch ============
__global__ __launch_bounds__(256) void k_zero(
    int* __restrict__ f4, int nf4, int* __restrict__ cnt, int N) {
  const int i = blockIdx.x * 256 + threadIdx.x;
  if (i < nf4) f4[i] = 0;
  if (i < N) cnt[i] = 0;
}

// ============ flagB pass ============
__global__ __launch_bounds__(256) void k_flag2(
    const int* __restrict__ sidx, const int* __restrict__ src,
    const int* __restrict__ dst, const int* __restrict__ aidx,
    unsigned char* __restrict__ flags, int NS, int B) {
  const int i = blockIdx.x * 256 + threadIdx.x;
  if (i < NS) {
    int e = sidx[i];
    flags[src[e]] = 1;
    flags[dst[e]] = 1;
  } else if (i < NS + B) {
    flags[aidx[i - NS]] = 1;
  }
}

// ============ flagA pass ============
__global__ __launch_bounds__(256) void k_flagA(
    const int* __restrict__ src, const int* __restrict__ dst,
    unsigned char* __restrict__ flags, int E) {
  const int e = blockIdx.x * 256 + threadIdx.x;
  if (e < E && (flags[dst[e]] & 1)) {
    int s = src[e];
    flags[s] = flags[s] | 2;  // benign race: all writers store same value
  }
}

// ============ shared MFMA GEMM body: yh[N x 64] = bf16(x @ W), bf16 output ============
// Layouts verified on-device: A: m=lane&15, k=16*g+4*(lane>>4)+..;
// D: row=(lane>>4)*4+reg, col=lane&15.
__device__ __forceinline__ void gemm_body(
    const float* __restrict__ x, const float* __restrict__ W,
    unsigned short* __restrict__ yh, int N, int bid, int nB) {
  __shared__ unsigned short wt[DD * DD];
  __shared__ float ys[4][16][68];
  for (int i = threadIdx.x; i < DD * DD; i += 256) {
    int k = i >> 6, n = i & 63;
    wt[n * DD + k] = f2bf(W[i]);
  }
  __syncthreads();
  const int wave = threadIdx.x >> 6;
  const int lane = threadIdx.x & 63;
  const int g = lane >> 4;
  const int m = lane & 15;
  bf16x8 bfr[8];
#pragma unroll
  for (int nt = 0; nt < 4; ++nt)
#pragma unroll
    for (int m2 = 0; m2 < 2; ++m2) {
      const int base = (nt * 16 + m) * DD + 4 * g + 32 * m2;
      ushort4 lo = *(const ushort4*)&wt[base];
      ushort4 hi = *(const ushort4*)&wt[base + 16];
      bf16x8 f;
      f[0] = (short)lo.x; f[1] = (short)lo.y; f[2] = (short)lo.z; f[3] = (short)lo.w;
      f[4] = (short)hi.x; f[5] = (short)hi.y; f[6] = (short)hi.z; f[7] = (short)hi.w;
      bfr[nt * 2 + m2] = f;
    }
  const int tiles = (N + 15) / 16;
  for (int t = bid * 4 + wave; t < tiles; t += nB * 4) {
    const int row = t * 16 + m;
    const int rsafe = (row < N) ? row : (N - 1);
    const float* xr = x + (size_t)rsafe * DD + 4 * g;
    float4 a0 = *(const float4*)(xr + 0);
    float4 a1 = *(const float4*)(xr + 16);
    float4 a2 = *(const float4*)(xr + 32);
    float4 a3 = *(const float4*)(xr + 48);
    bf16x8 af0, af1;
    af0[0] = (short)f2bf(a0.x); af0[1] = (short)f2bf(a0.y);
    af0[2] = (short)f2bf(a0.z); af0[3] = (short)f2bf(a0.w);
    af0[4] = (short)f2bf(a1.x); af0[5] = (short)f2bf(a1.y);
    af0[6] = (short)f2bf(a1.z); af0[7] = (short)f2bf(a1.w);
    af1[0] = (short)f2bf(a2.x); af1[1] = (short)f2bf(a2.y);
    af1[2] = (short)f2bf(a2.z); af1[3] = (short)f2bf(a2.w);
    af1[4] = (short)f2bf(a3.x); af1[5] = (short)f2bf(a3.y);
    af1[6] = (short)f2bf(a3.z); af1[7] = (short)f2bf(a3.w);
    f32x4 acc0 = {0.f, 0.f, 0.f, 0.f}, acc1 = acc0, acc2 = acc0, acc3 = acc0;
    acc0 = __builtin_amdgcn_mfma_f32_16x16x32_bf16(af0, bfr[0], acc0, 0, 0, 0);
    acc0 = __builtin_amdgcn_mfma_f32_16x16x32_bf16(af1, bfr[1], acc0, 0, 0, 0);
    acc1 = __builtin_amdgcn_mfma_f32_16x16x32_bf16(af0, bfr[2], acc1, 0, 0, 0);
    acc1 = __builtin_amdgcn_mfma_f32_16x16x32_bf16(af1, bfr[3], acc1, 0, 0, 0);
    acc2 = __builtin_amdgcn_mfma_f32_16x16x32_bf16(af0, bfr[4], acc2, 0, 0, 0);
    acc2 = __builtin_amdgcn_mfma_f32_16x16x32_bf16(af1, bfr[5], acc2, 0, 0, 0);
    acc3 = __builtin_amdgcn_mfma_f32_16x16x32_bf16(af0, bfr[6], acc3, 0, 0, 0);
    acc3 = __builtin_amdgcn_mfma_f32_16x16x32_bf16(af1, bfr[7], acc3, 0, 0, 0);
#pragma unroll
    for (int r = 0; r < 4; ++r) {
      ys[wave][4 * g + r][0 * 16 + m] = acc0[r];
      ys[wave][4 * g + r][1 * 16 + m] = acc1[r];
      ys[wave][4 * g + r][2 * 16 + m] = acc2[r];
      ys[wave][4 * g + r][3 * 16 + m] = acc3[r];
    }
    // same-wave cross-lane LDS RAW: compiler inserts lgkmcnt wait
    if (row < N) {
      unsigned short* yr = yh + (size_t)row * DD + g * 16;
      const float* s = &ys[wave][m][g * 16];
      uint4 olo, ohi;
      olo.x = pack2bf(s[0], s[1]);
      olo.y = pack2bf(s[2], s[3]);
      olo.z = pack2bf(s[4], s[5]);
      olo.w = pack2bf(s[6], s[7]);
      ohi.x = pack2bf(s[8], s[9]);
      ohi.y = pack2bf(s[10], s[11]);
      ohi.z = pack2bf(s[12], s[13]);
      ohi.w = pack2bf(s[14], s[15]);
      *(uint4*)yr = olo;
      *(uint4*)(yr + 8) = ohi;
    }
  }
}

// ============ fused: [0,GB) gemm1 | [GB,..) filtered CSR fill ============
// gemm1 (~16us, off critical path) hides inside the fill (~41us, atomic-bound):
// verified round 7 (combined 41.2us = fill-alone, MfmaUtil 0.66%).
__global__ __launch_bounds__(256) void k_pregf(
    const float* __restrict__ x, const float* __restrict__ W,
    unsigned short* __restrict__ yh, int N, int GB,
    const int* __restrict__ src, const int* __restrict__ dst,
    const unsigned char* __restrict__ flags, int* __restrict__ cnt,
    int* __restrict__ csr, int E) {
  const int bid = blockIdx.x;
  if (bid < GB) {
    gemm_body(x, W, yh, N, bid, GB);
  } else {
    int e = (bid - GB) * 256 + threadIdx.x;
    if (e < E) {
      int d = dst[e];
      if (flags[d]) {
        int slot = atomicAdd(&cnt[d], 1);
        if (slot < CAP) csr[d * CAP + slot] = src[e];
      }
    }
  }
}

// ============ fused gather1 + W1 transform (EXACT round-9 form, measured 46us) ====
// Round-10 (prefetch pipeline + masked batch: VGPR 24->52, 92us) and round-11
// (2-accumulator FMA split: VGPR 24->32, 49-52us) both REGRESSED vs this form.
// Lesson (4x confirmed): in latency-bound gather, minimal registers + simple
// codegen + occupancy beat manual ILP. Do not touch.
__global__ __launch_bounds__(256) void k_g1t(
    const unsigned short* __restrict__ yh0, const int* __restrict__ cnt,
    const int* __restrict__ csr, const float* __restrict__ b0,
    const float* __restrict__ W1, unsigned short* __restrict__ yh1, int N,
    const unsigned char* __restrict__ flags) {
  __shared__ __align__(16) float Ws[DD * DD];  // 16 KB
  __shared__ __align__(16) float xs[4][DD];
  for (int i = threadIdx.x; i < DD * DD; i += 256) Ws[i] = W1[i];
  __syncthreads();
  const int wave = threadIdx.x >> 6;
  const int lane = threadIdx.x & 63;
  const int h = lane >> 5;  // edge-parity member
  const int c = lane & 31;  // uint column (elems 2c, 2c+1)
  const float b0r = b0[2 * c];
  const float b1r = b0[2 * c + 1];
  for (int n = blockIdx.x * 4 + wave; n < N; n += gridDim.x * 4) {
    // --- single round: flags + cnt + all slots (mutually independent) ---
    const int fl = flags[n];
    int c2 = cnt[n];
    const int slot = csr[n * CAP + c];  // lane c holds slot c (mirrored in h=1)
    if (!(fl & 2)) continue;
    c2 = (c2 < CAP) ? c2 : CAP;
    float a0 = 0.f, a1 = 0.f;
    int j = 0;
    for (; j + 8 <= c2; j += 8) {
      const int sA = __shfl(slot, j + 0 + h);
      const int sB = __shfl(slot, j + 2 + h);
      const int sC = __shfl(slot, j + 4 + h);
      const int sD = __shfl(slot, j + 6 + h);
      unsigned vA = *(const unsigned*)&yh0[(size_t)sA * DD + 2 * c];
      unsigned vB = *(const unsigned*)&yh0[(size_t)sB * DD + 2 * c];
      unsigned vC = *(const unsigned*)&yh0[(size_t)sC * DD + 2 * c];
      unsigned vD = *(const unsigned*)&yh0[(size_t)sD * DD + 2 * c];
      a0 += (__uint_as_float(vA << 16) + __uint_as_float(vB << 16)) +
            (__uint_as_float(vC << 16) + __uint_as_float(vD << 16));
      a1 += (__uint_as_float(vA & 0xffff0000u) + __uint_as_float(vB & 0xffff0000u)) +
            (__uint_as_float(vC & 0xffff0000u) + __uint_as_float(vD & 0xffff0000u));
    }
    for (; j + 2 <= c2; j += 2) {
      const int sA = __shfl(slot, j + h);
      unsigned vA = *(const unsigned*)&yh0[(size_t)sA * DD + 2 * c];
      a0 += __uint_as_float(vA << 16);
      a1 += __uint_as_float(vA & 0xffff0000u);
    }
    const int sT = __shfl(slot, j);  // hoisted out of divergent branch
    if (j < c2 && h == 0) {
      unsigned vA = *(const unsigned*)&yh0[(size_t)sT * DD + 2 * c];
      a0 += __uint_as_float(vA << 16);
      a1 += __uint_as_float(vA & 0xffff0000u);
    }
    a0 += __shfl_xor(a0, 32);
    a1 += __shfl_xor(a1, 32);
    if (h == 0) {
      xs[wave][2 * c] = fmaxf(a0 + b0r, 0.f);
      xs[wave][2 * c + 1] = fmaxf(a1 + b1r, 0.f);
    }
    // same-wave cross-lane LDS RAW: compiler inserts lgkmcnt wait
    float acc = 0.f;
#pragma unroll
    for (int k4 = 0; k4 < 16; ++k4) {
      float4 h4 = *(const float4*)&xs[wave][k4 * 4];
      acc = fmaf(h4.x, Ws[(k4 * 4 + 0) * DD + lane], acc);
      acc = fmaf(h4.y, Ws[(k4 * 4 + 1) * DD + lane], acc);
      acc = fmaf(h4.z, Ws[(k4 * 4 + 2) * DD + lane], acc);
      acc = fmaf(h4.w, Ws[(k4 * 4 + 3) * DD + lane], acc);
    }
    yh1[(size_t)n * DD + lane] = f2bf(acc);  // 2B/lane contiguous: coalesced
  }
}

// ============ bf16 gather: out[n] = relu(b + sum yh[csr(n)]) ============
// Round-9 form.
__global__ __launch_bounds__(256) void k_gather_h(
    const unsigned short* __restrict__ yh, const int* __restrict__ cnt,
    const int* __restrict__ csr, const float* __restrict__ b,
    float* __restrict__ outp, int N, const unsigned char* __restrict__ flags,
    int bit) {
  const int wave = threadIdx.x >> 6;
  const int lane = threadIdx.x & 63;
  const int h = lane >> 5;  // edge-parity member
  const int c = lane & 31;  // uint column (elems 2c, 2c+1)
  const int n = blockIdx.x * 4 + wave;
  if (n >= N) return;
  if (!(flags[n] & bit)) return;
  const float b0r = b[2 * c];
  const float b1r = b[2 * c + 1];
  // one round: cnt + all slots (independent)
  int c2 = cnt[n];
  const int slot = csr[n * CAP + c];
  c2 = (c2 < CAP) ? c2 : CAP;
  float a0 = 0.f, a1 = 0.f;
  int j = 0;
  for (; j + 8 <= c2; j += 8) {
    const int sA = __shfl(slot, j + 0 + h);
    const int sB = __shfl(slot, j + 2 + h);
    const int sC = __shfl(slot, j + 4 + h);
    const int sD = __shfl(slot, j + 6 + h);
    unsigned vA = *(const unsigned*)&yh[(size_t)sA * DD + 2 * c];
    unsigned vB = *(const unsigned*)&yh[(size_t)sB * DD + 2 * c];
    unsigned vC = *(const unsigned*)&yh[(size_t)sC * DD + 2 * c];
    unsigned vD = *(const unsigned*)&yh[(size_t)sD * DD + 2 * c];
    a0 += (__uint_as_float(vA << 16) + __uint_as_float(vB << 16)) +
          (__uint_as_float(vC << 16) + __uint_as_float(vD << 16));
    a1 += (__uint_as_float(vA & 0xffff0000u) + __uint_as_float(vB & 0xffff0000u)) +
          (__uint_as_float(vC & 0xffff0000u) + __uint_as_float(vD & 0xffff0000u));
  }
  for (; j + 2 <= c2; j += 2) {
    const int sA = __shfl(slot, j + h);
    unsigned vA = *(const unsigned*)&yh[(size_t)sA * DD + 2 * c];
    a0 += __uint_as_float(vA << 16);
    a1 += __uint_as_float(vA & 0xffff0000u);
  }
  const int sT = __shfl(slot, j);
  if (j < c2 && h == 0) {
    unsigned vA = *(const unsigned*)&yh[(size_t)sT * DD + 2 * c];
    a0 += __uint_as_float(vA << 16);
    a1 += __uint_as_float(vA & 0xffff0000u);
  }
  a0 += __shfl_xor(a0, 32);
  a1 += __shfl_xor(a1, 32);
  if (h == 0) {
    float2 r;
    r.x = fmaxf(a0 + b0r, 0.f);
    r.y = fmaxf(a1 + b1r, 0.f);
    *(float2*)&outp[(size_t)n * DD + 2 * c] = r;
  }
}

// ======================= fallback atomic path =======================
__global__ __launch_bounds__(256) void k_transform(
    const float* __restrict__ x, const float* __restrict__ W,
    float* __restrict__ y, int n_rows, int relu_in) {
  __shared__ __align__(16) float Ws[DD * DD];
  __shared__ __align__(16) float xs[4][DD];
  for (int i = threadIdx.x; i < DD * DD; i += 256) Ws[i] = W[i];
  __syncthreads();
  const int wave = threadIdx.x >> 6;
  const int lane = threadIdx.x & 63;
  for (int n = blockIdx.x * 4 + wave; n < n_rows; n += gridDim.x * 4) {
    float xv = x[n * DD + lane];
    if (relu_in) xv = fmaxf(xv, 0.f);
    xs[wave][lane] = xv;
    float acc = 0.f;
#pragma unroll
    for (int k4 = 0; k4 < DD / 4; ++k4) {
      float4 h4 = *(const float4*)&xs[wave][k4 * 4];
      acc = fmaf(h4.x, Ws[(k4 * 4 + 0) * DD + lane], acc);
      acc = fmaf(h4.y, Ws[(k4 * 4 + 1) * DD + lane], acc);
      acc = fmaf(h4.z, Ws[(k4 * 4 + 2) * DD + lane], acc);
      acc = fmaf(h4.w, Ws[(k4 * 4 + 3) * DD + lane], acc);
    }
    y[n * DD + lane] = acc;
  }
}

__global__ __launch_bounds__(256) void k_init_bias(
    float4* __restrict__ acc, const float* __restrict__ b, int total4) {
  const float4* b4 = (const float4*)b;
  for (int i = blockIdx.x * blockDim.x + threadIdx.x; i < total4;
       i += gridDim.x * blockDim.x)
    acc[i] = b4[i & 15];
}

__global__ __launch_bounds__(256) void k_scatter(
    const float* __restrict__ y, const int* __restrict__ src,
    const int* __restrict__ dst, float* __restrict__ acc, int E) {
  const int total = E * 16;
  for (int i = blockIdx.x * blockDim.x + threadIdx.x; i < total;
       i += gridDim.x * blockDim.x) {
    int e = i >> 4;
    int d4 = (i & 15) << 2;
    int s = src[e], dd = dst[e];
    float4 v = *(const float4*)&y[s * DD + d4];
    float* ap = &acc[dd * DD + d4];
    unsafeAtomicAdd(ap + 0, v.x);
    unsafeAtomicAdd(ap + 1, v.y);
    unsafeAtomicAdd(ap + 2, v.z);
    unsafeAtomicAdd(ap + 3, v.w);
  }
}

__global__ __launch_bounds__(256) void k_relu_inplace(float* __restrict__ p, int n) {
  for (int i = blockIdx.x * blockDim.x + threadIdx.x; i < n;
       i += gridDim.x * blockDim.x)
    p[i] = fmaxf(p[i], 0.f);
}

// ---------------- memory-management head ----------------
__global__ __launch_bounds__(256) void k_mm_head(
    const float* __restrict__ xact, const float* __restrict__ rel,
    const int* __restrict__ src, const int* __restrict__ dst,
    const int* __restrict__ etype, const int* __restrict__ sidx,
    const float* __restrict__ W0, const float* __restrict__ b0,
    const float* __restrict__ W1, const float* __restrict__ b1,
    const float* __restrict__ Wadv, const float* __restrict__ badv,
    const float* __restrict__ Wval, const float* __restrict__ bval,
    float* __restrict__ out, int NS) {
  __shared__ __align__(16) float W0s[192 * DD];  // 48 KB
  __shared__ float Wadvs[DD * 3], Wvals[DD], b0s[DD], b1s[DD], badvs[3];
  __shared__ __align__(16) float hs[4][192];
  __shared__ __align__(16) float h1s[4][DD];
  for (int i = threadIdx.x; i < 192 * DD; i += 256) W0s[i] = W0[i];
  for (int i = threadIdx.x; i < DD * 3; i += 256) Wadvs[i] = Wadv[i];
  if (threadIdx.x < DD) {
    Wvals[threadIdx.x] = Wval[threadIdx.x];
    b0s[threadIdx.x] = b0[threadIdx.x];
    b1s[threadIdx.x] = b1[threadIdx.x];
  }
  if (threadIdx.x < 3) badvs[threadIdx.x] = badv[threadIdx.x];
  __syncthreads();
  const float bv = bval[0];
  const int wave = threadIdx.x >> 6;
  const int lane = threadIdx.x & 63;
  for (int i = blockIdx.x * 4 + wave; i < NS; i += gridDim.x * 4) {
    int e = sidx[i];
    int s = src[e], dd = dst[e], t = etype[e];
    hs[wave][lane] = fmaxf(xact[s * DD + lane], 0.f);
    hs[wave][64 + lane] = rel[t * DD + lane];
    hs[wave][128 + lane] = fmaxf(xact[dd * DD + lane], 0.f);
    float acc = b0s[lane];
#pragma unroll
    for (int k4 = 0; k4 < 48; ++k4) {
      float4 h4 = *(const float4*)&hs[wave][k4 * 4];
      acc = fmaf(h4.x, W0s[(k4 * 4 + 0) * DD + lane], acc);
      acc = fmaf(h4.y, W0s[(k4 * 4 + 1) * DD + lane], acc);
      acc = fmaf(h4.z, W0s[(k4 * 4 + 2) * DD + lane], acc);
      acc = fmaf(h4.w, W0s[(k4 * 4 + 3) * DD + lane], acc);
    }
    h1s[wave][lane] = fmaxf(acc, 0.f);
    float acc2 = b1s[lane];
#pragma unroll
    for (int k4 = 0; k4 < 16; ++k4) {
      float4 h4 = *(const float4*)&h1s[wave][k4 * 4];
      acc2 = fmaf(h4.x, W1[(k4 * 4 + 0) * DD + lane], acc2);
      acc2 = fmaf(h4.y, W1[(k4 * 4 + 1) * DD + lane], acc2);
      acc2 = fmaf(h4.z, W1[(k4 * 4 + 2) * DD + lane], acc2);
      acc2 = fmaf(h4.w, W1[(k4 * 4 + 3) * DD + lane], acc2);
    }
    float h2 = fmaxf(acc2, 0.f);
    float p0 = h2 * Wadvs[lane * 3 + 0];
    float p1 = h2 * Wadvs[lane * 3 + 1];
    float p2 = h2 * Wadvs[lane * 3 + 2];
    float pv = h2 * Wvals[lane];
#pragma unroll
    for (int off = 32; off; off >>= 1) {
      p0 += __shfl_xor(p0, off);
      p1 += __shfl_xor(p1, off);
      p2 += __shfl_xor(p2, off);
      pv += __shfl_xor(pv, off);
    }
    if (lane == 0) {
      float a0 = p0 + badvs[0], a1 = p1 + badvs[1], a2 = p2 + badvs[2];
      float val = pv + bv;
      float m = (a0 + a1 + a2) * (1.f / 3.f);
      out[i * 3 + 0] = val + a0 - m;
      out[i * 3 + 1] = val + a1 - m;
      out[i * 3 + 2] = val + a2 - m;
    }
  }
}

// ---------------- explore head ----------------
__global__ __launch_bounds__(256) void k_ex_head(
    const float* __restrict__ xact, const int* __restrict__ aidx,
    const float* __restrict__ W0, const float* __restrict__ b0,
    const float* __restrict__ W1, const float* __restrict__ b1,
    const float* __restrict__ Wadv, const float* __restrict__ badv,
    const float* __restrict__ Wval, const float* __restrict__ bval,
    float* __restrict__ out, int B) {
  __shared__ __align__(16) float W0s[DD * DD], W1s[DD * DD];
  __shared__ float Wadvs[DD * 5], Wvals[DD], b0s[DD], b1s[DD], badvs[5];
  __shared__ __align__(16) float hs[4][DD], h1s[4][DD];
  for (int i = threadIdx.x; i < DD * DD; i += 256) {
    W0s[i] = W0[i];
    W1s[i] = W1[i];
  }
  for (int i = threadIdx.x; i < DD * 5; i += 256) Wadvs[i] = Wadv[i];
  if (threadIdx.x < DD) {
    Wvals[threadIdx.x] = Wval[threadIdx.x];
    b0s[threadIdx.x] = b0[threadIdx.x];
    b1s[threadIdx.x] = b1[threadIdx.x];
  }
  if (threadIdx.x < 5) badvs[threadIdx.x] = badv[threadIdx.x];
  __syncthreads();
  const float bv = bval[0];
  const int wave = threadIdx.x >> 6;
  const int lane = threadIdx.x & 63;
  const int i = blockIdx.x * 4 + wave;
  if (i >= B) return;
  int n = aidx[i];
  hs[wave][lane] = fmaxf(xact[n * DD + lane], 0.f);
  float acc = b0s[lane];
#pragma unroll
  for (int k4 = 0; k4 < 16; ++k4) {
    float4 h4 = *(const float4*)&hs[wave][k4 * 4];
    acc = fmaf(h4.x, W0s[(k4 * 4 + 0) * DD + lane], acc);
    acc = fmaf(h4.y, W0s[(k4 * 4 + 1) * DD + lane], acc);
    acc = fmaf(h4.z, W0s[(k4 * 4 + 2) * DD + lane], acc);
    acc = fmaf(h4.w, W0s[(k4 * 4 + 3) * DD + lane], acc);
  }
  h1s[wave][lane] = fmaxf(acc, 0.f);
  float acc2 = b1s[lane];
#pragma unroll
  for (int k4 = 0; k4 < 16; ++k4) {
    float4 h4 = *(const float4*)&h1s[wave][k4 * 4];
    acc2 = fmaf(h4.x, W1s[(k4 * 4 + 0) * DD + lane], acc2);
    acc2 = fmaf(h4.y, W1s[(k4 * 4 + 1) * DD + lane], acc2);
    acc2 = fmaf(h4.z, W1s[(k4 * 4 + 2) * DD + lane], acc2);
    acc2 = fmaf(h4.w, W1s[(k4 * 4 + 3) * DD + lane], acc2);
  }
  float h2 = fmaxf(acc2, 0.f);
  float p[6];
#pragma unroll
  for (int c = 0; c < 5; ++c) p[c] = h2 * Wadvs[lane * 5 + c];
  p[5] = h2 * Wvals[lane];
#pragma unroll
  for (int off = 32; off; off >>= 1)
#pragma unroll
    for (int c = 0; c < 6; ++c) p[c] += __shfl_xor(p[c], off);
  if (lane == 0) {
    float a[5];
    float m = 0.f;
#pragma unroll
    for (int c = 0; c < 5; ++c) {
      a[c] = p[c] + badvs[c];
      m += a[c];
    }
    m *= 0.2f;
    float val = p[5] + bv;
#pragma unroll
    for (int c = 0; c < 5; ++c) out[i * 5 + c] = val + a[c] - m;
  }
}

extern "C" void kernel_launch(void* const* d_in, const int* in_sizes, int n_in,
                              void* d_out, int out_size, void* d_ws, size_t ws_size,
                              hipStream_t stream) {
  const float* ent = (const float*)d_in[0];
  const float* rel = (const float*)d_in[1];
  const float* gcnW = (const float*)d_in[2];
  const float* gcnB = (const float*)d_in[3];
  const float* mmW0 = (const float*)d_in[4];
  const float* mmB0 = (const float*)d_in[5];
  const float* mmW1 = (const float*)d_in[6];
  const float* mmB1 = (const float*)d_in[7];
  const float* mmWa = (const float*)d_in[8];
  const float* mmBa = (const float*)d_in[9];
  const float* mmWv = (const float*)d_in[10];
  const float* mmBv = (const float*)d_in[11];
  const float* exW0 = (const float*)d_in[12];
  const float* exB0 = (const float*)d_in[13];
  const float* exW1 = (const float*)d_in[14];
  const float* exB1 = (const float*)d_in[15];
  const float* exWa = (const float*)d_in[16];
  const float* exBa = (const float*)d_in[17];
  const float* exWv = (const float*)d_in[18];
  const float* exBv = (const float*)d_in[19];
  const int* eidx = (const int*)d_in[20];
  const int* etype = (const int*)d_in[21];
  const int* sidx = (const int*)d_in[22];
  const int* aidx = (const int*)d_in[23];

  const int N = in_sizes[0] / DD;
  const int E = in_sizes[20] / 2;
  const int NS = in_sizes[22];
  const int B = in_sizes[23];
  const int* src = eidx;
  const int* dst = eidx + E;

  // Workspace layout:
  //   bufA: N*DD f32. Lower half = yh0 (gemm1 out, bf16). Upper half = csr.
  //   bufB: N*DD f32 = x2 (gather2 out at flagB rows; heads input).
  //   cnt : N ints
  //   flags: N bytes (padded to 4B multiple)
  //   yh1 : N*DD bf16 (k_g1t out) -- separate region: k_g1t reads yh0 while
  //         writing yh1, so in-place reuse of yh0 would race.
  float* bufA = (float*)d_ws;
  float* bufB = bufA + (size_t)N * DD;
  int* cnt = (int*)(bufB + (size_t)N * DD);
  unsigned char* flags = (unsigned char*)(cnt + N);
  const int nf4 = (N + 3) / 4;
  unsigned short* yh0 = (unsigned short*)bufA;
  int* csr = (int*)d_ws + (size_t)N * DD / 2;  // bufA upper half
  unsigned short* yh1 = (unsigned short*)((int*)flags + nf4);
  const size_t need = ((size_t)2 * N * DD + (size_t)N) * 4 + (size_t)nf4 * 4 +
                      (size_t)N * DD * 2;

  float* q_mm = (float*)d_out;
  float* q_ex = q_mm + (size_t)NS * 3;

  dim3 blk(256);
  const int eb = (E + 255) / 256;
  const int GB = 512;  // gemm blocks in k_pregf

  if (ws_size >= need) {
    // ---- zero flags + cnt ----
    k_zero<<<(N + 255) / 256, blk, 0, stream>>>((int*)flags, nf4, cnt, N);
    // ---- flagB from heads' consumers ----
    k_flag2<<<(NS + B + 255) / 256, blk, 0, stream>>>(sidx, src, dst, aidx, flags,
                                                      NS, B);
    // ---- flagA edge pass ----
    k_flagA<<<eb, blk, 0, stream>>>(src, dst, flags, E);
    // ---- fused: gemm1 (ent@W0 -> yh0 bf16) | filtered CSR fill ----
    k_pregf<<<GB + eb, blk, 0, stream>>>(ent, gcnW, yh0, N, GB, src, dst, flags,
                                         cnt, csr, E);
    // ---- fused layer1 gather + W1 transform at flagA (bit 2) rows ----
    k_g1t<<<4096, blk, 0, stream>>>(yh0, cnt, csr, gcnB, gcnW + DD * DD, yh1, N,
                                    flags);
    // ---- layer 2 gather: x2 = relu(b1 + gather yh1) at flagB (bit 1) ----
    k_gather_h<<<(N + 3) / 4, blk, 0, stream>>>(yh1, cnt, csr, gcnB + DD, bufB, N,
                                                flags, 1);
    // ---- heads (x2 = bufB at flagB nodes; fmax idempotent) ----
    k_mm_head<<<256, blk, 0, stream>>>(bufB, rel, src, dst, etype, sidx, mmW0,
                                       mmB0, mmW1, mmB1, mmWa, mmBa, mmWv, mmBv,
                                       q_mm, NS);
    k_ex_head<<<(B + 3) / 4, blk, 0, stream>>>(bufB, aidx, exW0, exB0, exW1, exB1,
                                               exWa, exBa, exWv, exBv, q_ex, B);
  } else {
    // ---- fallback: atomic scatter path ----
    k_transform<<<1024, blk, 0, stream>>>(ent, gcnW, bufA, N, 0);
    k_init_bias<<<1024, blk, 0, stream>>>((float4*)bufB, gcnB, N * 16);
    k_scatter<<<2048, blk, 0, stream>>>(bufA, src, dst, bufB, E);
    k_transform<<<1024, blk, 0, stream>>>(bufB, gcnW + DD * DD, bufA, N, 1);
    k_init_bias<<<1024, blk, 0, stream>>>((float4*)bufB, gcnB + DD, N * 16);
    k_scatter<<<2048, blk, 0, stream>>>(bufA, src, dst, bufB, E);
    k_relu_inplace<<<1024, blk, 0, stream>>>(bufB, N * DD);
    k_mm_head<<<256, blk, 0, stream>>>(bufB, rel, src, dst, etype, sidx, mmW0,
                                       mmB0, mmW1, mmB1, mmWa, mmBa, mmWv, mmBv,
                                       q_mm, NS);
    k_ex_head<<<(B + 3) / 4, blk, 0, stream>>>(bufB, aidx, exW0, exB0, exW1, exB1,
                                               exWa, exBa, exWv, exBv, q_ex, B);
  }
}